// Round 1
// baseline (1726.094 us; speedup 1.0000x reference)
//
#include <hip/hip_runtime.h>

// Actor: state[B,10] -> 4x BiGRU(H=10,T=5,in=1) -> concat[40] -> l1(40->20,selu) -> l2(20->2) -> clip
// One thread per batch row. Weights staged in LDS (wave-uniform broadcast reads).

#define NH 10

__device__ __forceinline__ float fexp(float x) { return __expf(x); }               // v_exp_f32 path
__device__ __forceinline__ float frcp(float x) { return __builtin_amdgcn_rcpf(x); } // v_rcp_f32
__device__ __forceinline__ float fsigmoid(float x) { return frcp(1.0f + fexp(-x)); }
__device__ __forceinline__ float ftanh(float x) {
    // tanh(x) = 1 - 2/(exp(2x)+1); safe at both extremes (e->0 => -1, e->inf => 1)
    float e = fexp(2.0f * x);
    return 1.0f - 2.0f * frcp(e + 1.0f);
}

__global__ __launch_bounds__(256) void actor_kernel(
    const float* __restrict__ state,
    const float* __restrict__ wih0, const float* __restrict__ whh0,
    const float* __restrict__ bih0, const float* __restrict__ bhh0,
    const float* __restrict__ wih1, const float* __restrict__ whh1,
    const float* __restrict__ bih1, const float* __restrict__ bhh1,
    const float* __restrict__ wih2, const float* __restrict__ whh2,
    const float* __restrict__ bih2, const float* __restrict__ bhh2,
    const float* __restrict__ wih3, const float* __restrict__ whh3,
    const float* __restrict__ bih3, const float* __restrict__ bhh3,
    const float* __restrict__ l1w, const float* __restrict__ l1b,
    const float* __restrict__ l2w, const float* __restrict__ l2b,
    float* __restrict__ out, int Btot)
{
    // LDS staging (all reads later are wave-uniform -> broadcast, no bank conflicts)
    __shared__ __align__(16) float s_whh[4][30][12];  // rows padded 10->12 floats (48B, 16B-aligned)
    __shared__ float s_wih[4][30];
    __shared__ float s_bih[4][30];
    __shared__ float s_bhh[4][30];
    __shared__ __align__(16) float s_l1w[20][40];
    __shared__ float s_l1b[20];
    __shared__ float s_l2w[2][20];
    __shared__ float s_l2b[2];

    const int tid = threadIdx.x;

#define LOAD_DIR(d, wih, whh, bih, bhh)                                         \
    for (int i = tid; i < 300; i += 256) s_whh[d][i / 10][i % 10] = whh[i];     \
    for (int i = tid; i < 30; i += 256) {                                       \
        s_wih[d][i] = wih[i]; s_bih[d][i] = bih[i]; s_bhh[d][i] = bhh[i];       \
    }

    LOAD_DIR(0, wih0, whh0, bih0, bhh0)
    LOAD_DIR(1, wih1, whh1, bih1, bhh1)
    LOAD_DIR(2, wih2, whh2, bih2, bhh2)
    LOAD_DIR(3, wih3, whh3, bih3, bhh3)
#undef LOAD_DIR
    for (int i = tid; i < 800; i += 256) s_l1w[i / 40][i % 40] = l1w[i];
    for (int i = tid; i < 20; i += 256) s_l1b[i] = l1b[i];
    for (int i = tid; i < 40; i += 256) s_l2w[i / 20][i % 20] = l2w[i];
    for (int i = tid; i < 2; i += 256) s_l2b[i] = l2b[i];
    __syncthreads();

    const int b = blockIdx.x * 256 + tid;
    if (b >= Btot) return;

    // Load this row's 10 state values; keep halves in separate statically-indexed arrays.
    float xf[5], xs[5];
    {
        const float* srow = state + (size_t)b * 10;
#pragma unroll
        for (int i = 0; i < 5; ++i) xf[i] = srow[i];
#pragma unroll
        for (int i = 0; i < 5; ++i) xs[i] = srow[5 + i];
    }

    // l1 accumulator (selu applied at the end); avoids materializing feats[40]
    float a1[20];
#pragma unroll
    for (int o = 0; o < 20; ++o) a1[o] = s_l1b[o];

    // 4 directions: d=0: grp1 fwd, d=1: grp1 bwd, d=2: grp2 fwd, d=3: grp2 bwd
#pragma unroll 1
    for (int d = 0; d < 4; ++d) {
        const int rev = d & 1;
        const int grp2 = (d >= 2);

        float h[NH];
#pragma unroll
        for (int j = 0; j < NH; ++j) h[j] = 0.0f;

#pragma unroll
        for (int tt = 0; tt < 5; ++tt) {
            // pick x_t with compile-time indices only (tt unrolled)
            float xa = rev ? xf[4 - tt] : xf[tt];
            float xb = rev ? xs[4 - tt] : xs[tt];
            float xt = grp2 ? xb : xa;

            // gh = W_hh * h + b_hh   (30 outputs, K=10)
            float acc[30];
#pragma unroll
            for (int g = 0; g < 30; ++g) {
                float a = s_bhh[d][g];
#pragma unroll
                for (int k = 0; k < NH; ++k) a = fmaf(s_whh[d][g][k], h[k], a);
                acc[g] = a;
            }
            // gates
#pragma unroll
            for (int j = 0; j < NH; ++j) {
                float r = fsigmoid(fmaf(xt, s_wih[d][j], s_bih[d][j]) + acc[j]);
                float z = fsigmoid(fmaf(xt, s_wih[d][j + 10], s_bih[d][j + 10]) + acc[j + 10]);
                float n = ftanh(fmaf(xt, s_wih[d][j + 20], s_bih[d][j + 20]) + r * acc[j + 20]);
                h[j] = n + z * (h[j] - n);   // (1-z)*n + z*h
            }
        }

        // accumulate this direction's contribution to l1: a1[o] += sum_j h[j]*l1w[o][d*10+j]
#pragma unroll
        for (int o = 0; o < 20; ++o) {
            float s = a1[o];
#pragma unroll
            for (int j = 0; j < NH; ++j) s = fmaf(h[j], s_l1w[o][d * 10 + j], s);
            a1[o] = s;
        }
    }

    // SELU
    const float SC = 1.0507009873554805f;
    const float AL = 1.6732632423543772f;
#pragma unroll
    for (int o = 0; o < 20; ++o) {
        float s = a1[o];
        a1[o] = (s > 0.0f) ? SC * s : SC * AL * (fexp(s) - 1.0f);
    }

    // l2 (20 -> 2) + clip
    float o0 = s_l2b[0], o1 = s_l2b[1];
#pragma unroll
    for (int i = 0; i < 20; ++i) {
        o0 = fmaf(a1[i], s_l2w[0][i], o0);
        o1 = fmaf(a1[i], s_l2w[1][i], o1);
    }
    o0 = fminf(1.0f, fmaxf(-1.0f, o0));
    o1 = fminf(1.0f, fmaxf(-1.0f, o1));

    reinterpret_cast<float2*>(out)[b] = make_float2(o0, o1);
}

extern "C" void kernel_launch(void* const* d_in, const int* in_sizes, int n_in,
                              void* d_out, int out_size, void* d_ws, size_t ws_size,
                              hipStream_t stream) {
    const float* state = (const float*)d_in[0];
    const int B = in_sizes[0] / 10;
    const int grid = (B + 255) / 256;

    actor_kernel<<<grid, 256, 0, stream>>>(
        state,
        (const float*)d_in[1],  (const float*)d_in[2],  (const float*)d_in[3],  (const float*)d_in[4],
        (const float*)d_in[5],  (const float*)d_in[6],  (const float*)d_in[7],  (const float*)d_in[8],
        (const float*)d_in[9],  (const float*)d_in[10], (const float*)d_in[11], (const float*)d_in[12],
        (const float*)d_in[13], (const float*)d_in[14], (const float*)d_in[15], (const float*)d_in[16],
        (const float*)d_in[17], (const float*)d_in[18], (const float*)d_in[19], (const float*)d_in[20],
        (float*)d_out, B);
}